// Round 3
// baseline (411.393 us; speedup 1.0000x reference)
//
#include <hip/hip_runtime.h>
#include <math.h>

#define NRAYS 65536
#define T0N 128
#define T1N 64
#define CN 16
#define RPB 4                   // rays (waves) per block
#define NBLK (NRAYS / RPB)      // 16384

#define IMG_OFF   0
#define DEPTH_OFF (NRAYS * 3)
#define FXYZ_OFF  (NRAYS * 4)
#define PROP_OFF  (NRAYS * 7)
#define DIST_OFF  (NRAYS * 7 + 1)

// ---- DPP cross-lane (VALU pipe, zero LDS traffic) ----
template <int CTRL, int RM, int BM, bool BC>
__device__ __forceinline__ float dpp_add(float x) {
  int t = __builtin_amdgcn_update_dpp(0, __float_as_int(x), CTRL, RM, BM, BC);
  return x + __int_as_float(t);
}

// inclusive prefix sum over 64 lanes (gfx9 DPP scan idiom)
__device__ __forceinline__ float scan_incl(float x) {
  x = dpp_add<0x111, 0xF, 0xF, true>(x);   // row_shr:1
  x = dpp_add<0x112, 0xF, 0xF, true>(x);   // row_shr:2
  x = dpp_add<0x114, 0xF, 0xF, true>(x);   // row_shr:4
  x = dpp_add<0x118, 0xF, 0xF, true>(x);   // row_shr:8
  x = dpp_add<0x142, 0xA, 0xF, false>(x);  // row_bcast:15 -> rows 1,3
  x = dpp_add<0x143, 0xC, 0xF, false>(x);  // row_bcast:31 -> rows 2,3
  return x;
}

// wave sum; total valid ONLY in lanes 48..63 (row 3)
__device__ __forceinline__ float reduce_hi(float x) {
  x = dpp_add<0xB1, 0xF, 0xF, true>(x);    // quad_perm [1,0,3,2] (xor1)
  x = dpp_add<0x4E, 0xF, 0xF, true>(x);    // quad_perm [2,3,0,1] (xor2)
  x = dpp_add<0x141, 0xF, 0xF, true>(x);   // row_half_mirror (xor4-equiv)
  x = dpp_add<0x140, 0xF, 0xF, true>(x);   // row_mirror (xor8-equiv)
  x = dpp_add<0x142, 0xA, 0xF, false>(x);  // bcast15
  x = dpp_add<0x143, 0xC, 0xF, false>(x);  // bcast31 -> row3 = total
  return x;
}

__device__ __forceinline__ float rl63(float x) {  // broadcast lane63 via SALU
  return __int_as_float(__builtin_amdgcn_readlane(__float_as_int(x), 63));
}

// Wave-internal LDS producer->consumer sync (arrays are wave-private):
// waits lgkmcnt only, does NOT drain vmcnt like __syncthreads.
__device__ __forceinline__ void wave_lds_sync() {
  __builtin_amdgcn_wave_barrier();
  __builtin_amdgcn_fence(__ATOMIC_ACQ_REL, "workgroup");
  __builtin_amdgcn_wave_barrier();
}

__device__ __forceinline__ float spacing_fn(float x) {
  return (x < 1.0f) ? (x * 0.5f) : (1.0f - 1.0f / (2.0f * x));
}
__device__ __forceinline__ float spacing_inv_fn(float x) {
  return (x < 0.5f) ? (2.0f * x) : (1.0f / (2.0f - 2.0f * x));
}

// Branchless fixed-step searchsorted(side='right'): count of a[i] <= v.
// Requires a[] padded with sentinels > any v out to index pos_max+W0/2-1.
template <int W0>
__device__ __forceinline__ int count_le(const float* a, float v) {
  int pos = 0;
#pragma unroll
  for (int w = W0; w > 0; w >>= 1) pos += (a[pos + w - 1] <= v) ? w : 0;
  return pos;
}

__global__ void __launch_bounds__(256) nerf_main(
    const float* __restrict__ rays_o, const float* __restrict__ rays_d,
    const float* __restrict__ aabb, const float* __restrict__ sig_c,
    const float* __restrict__ sig_f, const float* __restrict__ colors,
    const float* __restrict__ w_view, const float* __restrict__ b_view,
    float* __restrict__ out, float* __restrict__ ws_partials, int use_atomic) {
  __shared__ float s_cdf[RPB][256];    // 129 real + sentinel pad (2.0f)
  __shared__ float s_bins1[RPB][129];  // 65 real + sentinel pad
  __shared__ float s_cw1[RPB][65];
  __shared__ float s_scal[RPB][2];

  const int wv = threadIdx.x >> 6;
  const int lane = threadIdx.x & 63;
  const int ray = blockIdx.x * RPB + wv;

  // ---- prefetch colors (4x 1KiB coalesced float4/wave) + sigmas; consumed late
  const int tg = lane >> 2, cg = lane & 3;
  const float4* col4 = (const float4*)(colors + (size_t)ray * (T1N * CN));
  const float4 cva = col4[(tg + 0) * 4 + cg];
  const float4 cvb = col4[(tg + 16) * 4 + cg];
  const float4 cvc = col4[(tg + 32) * 4 + cg];
  const float4 cvd = col4[(tg + 48) * 4 + cg];
  const float2 sg = ((const float2*)sig_c)[ray * 64 + lane];
  const float sgf = sig_f[ray * 64 + lane];

  // ---- ray setup
  float ro[3], rd[3];
#pragma unroll
  for (int c = 0; c < 3; ++c) { ro[c] = rays_o[ray * 3 + c]; rd[c] = rays_d[ray * 3 + c]; }
  float near = -3.0e38f, far = 3.0e38f;
#pragma unroll
  for (int c = 0; c < 3; ++c) {
    float dd = rd[c] + 1e-15f;
    float ta = (aabb[c] - ro[c]) / dd;
    float tb = (aabb[c + 3] - ro[c]) / dd;
    near = fmaxf(near, fminf(ta, tb));
    far = fminf(far, fmaxf(ta, tb));
  }
  if (far < near) { near = 1e9f; far = 1e9f; }
  near = fmaxf(near, 0.05f);
  const float s_near = spacing_fn(near), s_far = spacing_fn(far);

  // ---- coarse level: lane owns bins0 samples 2l, 2l+1
  const int i0 = 2 * lane, i1 = 2 * lane + 1;
  const float b_a = (float)i0 * (1.0f / 128.0f);
  const float b_b = (float)i1 * (1.0f / 128.0f);
  const float b_c = (float)(i1 + 1) * (1.0f / 128.0f);
  const float rb_a = spacing_inv_fn(s_near * (1.0f - b_a) + s_far * b_a);
  const float rb_b = spacing_inv_fn(s_near * (1.0f - b_b) + s_far * b_b);
  const float rb_c = spacing_inv_fn(s_near * (1.0f - b_c) + s_far * b_c);
  const float ds0 = (rb_b - rb_a) * sg.x;
  const float ds1 = (rb_c - rb_b) * sg.y;
  const float Spr = scan_incl(ds0 + ds1);
  const float E0 = Spr - (ds0 + ds1);
  const float e0 = __expf(-E0);
  const float ed0 = __expf(-ds0);
  float w00 = (1.0f - ed0) * e0;
  float w01 = (1.0f - __expf(-ds1)) * (e0 * ed0);
  if (w00 != w00) w00 = 0.0f;  // nan_to_num
  if (w01 != w01) w01 = 0.0f;

  // ---- pdf/cdf: one scan, total from lane 63 via readlane (SALU)
  const float wp0 = w00 + 0.01f, wp1 = w01 + 0.01f;
  const float S2 = scan_incl(wp0 + wp1);
  const float rt = 1.0f / rl63(S2);
  s_cdf[wv][i0 + 1] = fminf((S2 - wp1) * rt, 1.0f);
  s_cdf[wv][i1 + 1] = fminf(S2 * rt, 1.0f);
  if (lane == 0) s_cdf[wv][0] = 0.0f;
  s_cdf[wv][129 + lane] = 2.0f;                       // sentinel pad 129..192
  if (lane < 63) s_cdf[wv][193 + lane] = 2.0f;        // sentinel pad 193..255
  wave_lds_sync();

  // ---- inverse-CDF sampling of 65 new bins (branchless 8-step search)
  auto sample_one = [&](int j) -> float {
    const float u = ((float)j + 0.5f) * (1.0f / 65.0f);
    const int c = count_le<128>(&s_cdf[wv][0], u);    // inds in [1,128]
    const float c0 = s_cdf[wv][c - 1], c1 = s_cdf[wv][c];
    const float b0 = (float)(c - 1) * (1.0f / 128.0f);
    float t = (u - c0) / (c1 - c0);
    t = fminf(fmaxf(t, 0.0f), 1.0f);  // NaN->0, inf->1 == nan_to_num+clip
    const float bvv = b0 + t * (1.0f / 128.0f);
    s_bins1[wv][j] = bvv;
    return bvv;
  };
  const float bv = sample_one(lane);
  float bv64 = 0.0f;
  if (lane == 63) bv64 = sample_one(64);
  s_bins1[wv][65 + lane] = 2.0f;                      // sentinel pad 65..128
  float bvn = __shfl_down(bv, 1, 64);                 // bins1[lane+1]
  if (lane == 63) bvn = bv64;

  // ---- fine level: lane owns sample t=lane
  const float rbl  = spacing_inv_fn(s_near * (1.0f - bv)  + s_far * bv);
  const float rbl1 = spacing_inv_fn(s_near * (1.0f - bvn) + s_far * bvn);
  const float dsf = (rbl1 - rbl) * sgf;
  const float Sf = scan_incl(dsf);
  float w1 = (1.0f - __expf(-dsf)) * __expf(-(Sf - dsf));
  if (w1 != w1) w1 = 0.0f;
  const float tmid = 0.5f * (rbl + rbl1);

  // xyz + MERF contraction
  float px = ro[0] + rd[0] * tmid;
  float py = ro[1] + rd[1] * tmid;
  float pz = ro[2] + rd[2] * tmid;
  float cx = px, cy = py, cz = pz;
  {
    float ax = fabsf(px), ay = fabsf(py), az = fabsf(pz);
    float mag = fmaxf(ax, fmaxf(ay, az));
    if (mag >= 1.0f) {
      float inv = 1.0f / mag;
      float so = (2.0f - inv) * inv;
      int idx = (ax >= ay && ax >= az) ? 0 : ((ay >= az) ? 1 : 2);
      cx = px * (idx == 0 ? so : inv);
      cy = py * (idx == 1 ? so : inv);
      cz = pz * (idx == 2 ? so : inv);
    }
  }

  const float Scw = scan_incl(w1);
  const float wsum = rl63(Scw);
  const float depth_h = reduce_hi(w1 * tmid);   // totals valid lanes 48-63
  const float fx_h = reduce_hi(w1 * cx);
  const float fy_h = reduce_hi(w1 * cy);
  const float fz_h = reduce_hi(w1 * cz);
  s_cw1[wv][lane + 1] = Scw;
  if (lane == 0) s_cw1[wv][0] = 0.0f;

  // ---- distortion loss
  const float interval = bvn - bv;
  const float mid = bv + interval * 0.5f;
  const float wm = w1 * mid;
  const float Swm = scan_incl(wm);
  const float dl = (1.0f / 3.0f) * (interval * w1 * w1) +
                   2.0f * (wm * (Scw - w1) - w1 * (Swm - wm));
  const float dist_h = reduce_hi(dl);
  wave_lds_sync();  // covers s_bins1(+pad) and s_cw1 before interlevel reads

  // ---- interlevel loss: lane handles i = 2l, 2l+1 (branchless 7-step searches)
  float prop_lane = 0.0f;
  {
    const float* b1p = &s_bins1[wv][0];
    const float* cwp = &s_cw1[wv][0];
#pragma unroll
    for (int k = 0; k < 2; ++k) {
      int i = 2 * lane + k;
      float w0v = (k == 0) ? w00 : w01;
      float vlo = (float)i * (1.0f / 128.0f);
      float vhi = (float)(i + 1) * (1.0f / 128.0f);
      int ilo = max(min(count_le<64>(b1p, vlo) - 1, 63), 0);
      int ihi = min(count_le<64>(b1p + 1, vhi), 63);
      float wint = cwp[ihi + 1] - cwp[ilo];
      float diff = fmaxf(w0v - wint, 0.0f);
      prop_lane += diff * diff / (w0v + 1e-8f);
    }
  }
  const float prop_h = reduce_hi(prop_lane);

  // ---- color pipeline: fuse w_view matvec BEFORE the wave reduction, so the
  // only cross-lane work is one 3-scalar DPP reduction (no f_image reduce).
  float acc0, acc1, acc2;
  {
    const float wv0 = __shfl(w1, tg, 64);
    const float wv1 = __shfl(w1, tg + 16, 64);
    const float wv2 = __shfl(w1, tg + 32, 64);
    const float wv3 = __shfl(w1, tg + 48, 64);
    const float a0 = fmaf(wv0, cva.x, fmaf(wv1, cvb.x, fmaf(wv2, cvc.x, wv3 * cvd.x)));
    const float a1 = fmaf(wv0, cva.y, fmaf(wv1, cvb.y, fmaf(wv2, cvc.y, wv3 * cvd.y)));
    const float a2 = fmaf(wv0, cva.z, fmaf(wv1, cvb.z, fmaf(wv2, cvc.z, wv3 * cvd.z)));
    const float a3 = fmaf(wv0, cva.w, fmaf(wv1, cvb.w, fmaf(wv2, cvc.w, wv3 * cvd.w)));
    const float* wvp = w_view + cg * 12;  // rows for channels 4cg..4cg+3
    acc0 = reduce_hi(fmaf(a0, wvp[0], fmaf(a1, wvp[3], fmaf(a2, wvp[6], a3 * wvp[9]))));
    acc1 = reduce_hi(fmaf(a0, wvp[1], fmaf(a1, wvp[4], fmaf(a2, wvp[7], a3 * wvp[10]))));
    acc2 = reduce_hi(fmaf(a0, wvp[2], fmaf(a1, wvp[5], fmaf(a2, wvp[8], a3 * wvp[11]))));
  }

  // ---- epilogue: totals live in lanes 48-63; spread writes over 48-52
  if (lane >= 48 && lane < 51) {
    const int j = lane - 48;
    float acc = (j == 0) ? acc0 : ((j == 1) ? acc1 : acc2);
    acc += b_view[j];
    out[IMG_OFF + ray * 3 + j] = 1.0f / (1.0f + __expf(-acc)) + (1.0f - wsum);
    out[FXYZ_OFF + ray * 3 + j] = (j == 0) ? fx_h : ((j == 1) ? fy_h : fz_h);
  }
  if (lane == 51) out[DEPTH_OFF + ray] = depth_h;
  if (lane == 52) { s_scal[wv][0] = prop_h; s_scal[wv][1] = dist_h; }
  __syncthreads();  // only cross-wave communication in the kernel
  if (threadIdx.x == 0) {
    float P = s_scal[0][0] + s_scal[1][0] + s_scal[2][0] + s_scal[3][0];
    float D = s_scal[0][1] + s_scal[1][1] + s_scal[2][1] + s_scal[3][1];
    if (use_atomic) {
      atomicAdd(out + PROP_OFF, P * (1.0f / ((float)NRAYS * 128.0f)));
      atomicAdd(out + DIST_OFF, D * (1.0f / (float)NRAYS));
    } else {
      ws_partials[blockIdx.x] = P;
      ws_partials[NBLK + blockIdx.x] = D;
    }
  }
}

__device__ __forceinline__ float wave_sum_shfl(float x) {
#pragma unroll
  for (int off = 1; off < 64; off <<= 1) x += __shfl_xor(x, off, 64);
  return x;
}

__global__ void __launch_bounds__(256) reduce_partials(const float* __restrict__ ws,
                                                       float* __restrict__ out) {
  const float4* w4 = (const float4*)ws;
  float p = 0.0f, d = 0.0f;
  for (int i = threadIdx.x; i < NBLK / 4; i += 256) {
    float4 a = w4[i];
    p += (a.x + a.y) + (a.z + a.w);
    float4 b = w4[NBLK / 4 + i];
    d += (b.x + b.y) + (b.z + b.w);
  }
  p = wave_sum_shfl(p);
  d = wave_sum_shfl(d);
  __shared__ float sp[4], sd[4];
  const int wv = threadIdx.x >> 6, lane = threadIdx.x & 63;
  if (lane == 0) { sp[wv] = p; sd[wv] = d; }
  __syncthreads();
  if (threadIdx.x == 0) {
    float P = sp[0] + sp[1] + sp[2] + sp[3];
    float D = sd[0] + sd[1] + sd[2] + sd[3];
    out[PROP_OFF] = P * (1.0f / ((float)NRAYS * 128.0f));
    out[DIST_OFF] = D * (1.0f / (float)NRAYS);
  }
}

extern "C" void kernel_launch(void* const* d_in, const int* in_sizes, int n_in,
                              void* d_out, int out_size, void* d_ws, size_t ws_size,
                              hipStream_t stream) {
  const float* rays_o = (const float*)d_in[0];
  const float* rays_d = (const float*)d_in[1];
  const float* aabb = (const float*)d_in[2];
  const float* sig_c = (const float*)d_in[3];
  const float* sig_f = (const float*)d_in[4];
  const float* colors = (const float*)d_in[5];
  const float* w_view = (const float*)d_in[6];
  const float* b_view = (const float*)d_in[7];
  float* out = (float*)d_out;
  float* wsf = (float*)d_ws;

  const bool use_ws = (ws_size >= (size_t)(2 * NBLK) * sizeof(float)) && (wsf != nullptr);
  if (!use_ws) {
    hipMemsetAsync(out + PROP_OFF, 0, 2 * sizeof(float), stream);
  }
  nerf_main<<<NBLK, 256, 0, stream>>>(rays_o, rays_d, aabb, sig_c, sig_f, colors,
                                      w_view, b_view, out, wsf, use_ws ? 0 : 1);
  if (use_ws) reduce_partials<<<1, 256, 0, stream>>>(wsf, out);
}

// Round 4
// 408.363 us; speedup vs baseline: 1.0074x; 1.0074x over previous
//
#include <hip/hip_runtime.h>
#include <math.h>

#define NRAYS 65536
#define T0N 128
#define T1N 64
#define CN 16
#define RPB 4                   // rays (waves) per block
#define NBLK (NRAYS / RPB)      // 16384

#define IMG_OFF   0
#define DEPTH_OFF (NRAYS * 3)
#define FXYZ_OFF  (NRAYS * 4)
#define PROP_OFF  (NRAYS * 7)
#define DIST_OFF  (NRAYS * 7 + 1)

// v_rcp_f32: 1-ulp reciprocal. Output threshold is 1.57e-2 absolute with 4x
// margin at fp32-divide precision — 2^-22 relative error is invisible here.
// NaN/inf semantics match the divide paths we replace: 0*inf=NaN (0/0),
// pos*inf=inf (x/0) — both then shaped by the same fmin/fmax clamps.
__device__ __forceinline__ float frcp(float x) { return __builtin_amdgcn_rcpf(x); }

// ---- DPP cross-lane (VALU pipe, zero LDS traffic) ----
template <int CTRL, int RM, int BM, bool BC>
__device__ __forceinline__ float dpp_add(float x) {
  int t = __builtin_amdgcn_update_dpp(0, __float_as_int(x), CTRL, RM, BM, BC);
  return x + __int_as_float(t);
}

// inclusive prefix sum over 64 lanes (gfx9 DPP scan idiom)
__device__ __forceinline__ float scan_incl(float x) {
  x = dpp_add<0x111, 0xF, 0xF, true>(x);   // row_shr:1
  x = dpp_add<0x112, 0xF, 0xF, true>(x);   // row_shr:2
  x = dpp_add<0x114, 0xF, 0xF, true>(x);   // row_shr:4
  x = dpp_add<0x118, 0xF, 0xF, true>(x);   // row_shr:8
  x = dpp_add<0x142, 0xA, 0xF, false>(x);  // row_bcast:15 -> rows 1,3
  x = dpp_add<0x143, 0xC, 0xF, false>(x);  // row_bcast:31 -> rows 2,3
  return x;
}

// wave sum; total valid ONLY in lanes 48..63 (row 3)
__device__ __forceinline__ float reduce_hi(float x) {
  x = dpp_add<0xB1, 0xF, 0xF, true>(x);    // quad_perm xor1
  x = dpp_add<0x4E, 0xF, 0xF, true>(x);    // quad_perm xor2
  x = dpp_add<0x141, 0xF, 0xF, true>(x);   // row_half_mirror
  x = dpp_add<0x140, 0xF, 0xF, true>(x);   // row_mirror
  x = dpp_add<0x142, 0xA, 0xF, false>(x);  // bcast15
  x = dpp_add<0x143, 0xC, 0xF, false>(x);  // bcast31 -> row3 = total
  return x;
}

__device__ __forceinline__ float rl63(float x) {  // broadcast lane63 via SALU
  return __int_as_float(__builtin_amdgcn_readlane(__float_as_int(x), 63));
}

// Wave-internal LDS producer->consumer sync (arrays are wave-private):
// waits lgkmcnt only, does NOT drain vmcnt like __syncthreads.
__device__ __forceinline__ void wave_lds_sync() {
  __builtin_amdgcn_wave_barrier();
  __builtin_amdgcn_fence(__ATOMIC_ACQ_REL, "workgroup");
  __builtin_amdgcn_wave_barrier();
}

__device__ __forceinline__ float spacing_fn(float x) {
  return (x < 1.0f) ? (x * 0.5f) : (1.0f - 0.5f * frcp(x));
}
__device__ __forceinline__ float spacing_inv_fn(float x) {
  return (x < 0.5f) ? (2.0f * x) : frcp(2.0f - 2.0f * x);
}

// Branchless fixed-step searchsorted(side='right'): count of a[i] <= v.
// Requires a[] sorted with sentinels > any v through the max probe index.
template <int W0>
__device__ __forceinline__ int count_le(const float* a, float v) {
  int pos = 0;
#pragma unroll
  for (int w = W0; w > 0; w >>= 1) pos += (a[pos + w - 1] <= v) ? w : 0;
  return pos;
}

__global__ void __launch_bounds__(256) nerf_main(
    const float* __restrict__ rays_o, const float* __restrict__ rays_d,
    const float* __restrict__ aabb, const float* __restrict__ sig_c,
    const float* __restrict__ sig_f, const float* __restrict__ colors,
    const float* __restrict__ w_view, const float* __restrict__ b_view,
    float* __restrict__ out, float* __restrict__ ws_partials, int use_atomic) {
  __shared__ float s_cdf[RPB][224];    // 129 real + sentinels to idx 192 (max probe 191)
  __shared__ float s_bins1[RPB][129];  // 65 real + sentinel pad
  __shared__ float s_cw1[RPB][65];
  __shared__ float s_scal[RPB][2];

  const int wv = threadIdx.x >> 6;
  const int lane = threadIdx.x & 63;
  const int ray = blockIdx.x * RPB + wv;

  // ---- prefetch colors (4x 1KiB coalesced float4/wave) + sigmas; consumed late
  const int tg = lane >> 2, cg = lane & 3;
  const float4* col4 = (const float4*)(colors + (size_t)ray * (T1N * CN));
  const float4 cva = col4[(tg + 0) * 4 + cg];
  const float4 cvb = col4[(tg + 16) * 4 + cg];
  const float4 cvc = col4[(tg + 32) * 4 + cg];
  const float4 cvd = col4[(tg + 48) * 4 + cg];
  const float2 sg = ((const float2*)sig_c)[ray * 64 + lane];
  const float sgf = sig_f[ray * 64 + lane];

  // ---- ray setup (rcp instead of full-precision divide)
  float ro[3], rd[3];
#pragma unroll
  for (int c = 0; c < 3; ++c) { ro[c] = rays_o[ray * 3 + c]; rd[c] = rays_d[ray * 3 + c]; }
  float near = -3.0e38f, far = 3.0e38f;
#pragma unroll
  for (int c = 0; c < 3; ++c) {
    const float rdd = frcp(rd[c] + 1e-15f);
    float ta = (aabb[c] - ro[c]) * rdd;
    float tb = (aabb[c + 3] - ro[c]) * rdd;
    near = fmaxf(near, fminf(ta, tb));
    far = fminf(far, fmaxf(ta, tb));
  }
  if (far < near) { near = 1e9f; far = 1e9f; }
  near = fmaxf(near, 0.05f);
  const float s_near = spacing_fn(near), s_far = spacing_fn(far);

  // ---- coarse level: lane owns bins0 samples 2l, 2l+1
  const int i0 = 2 * lane, i1 = 2 * lane + 1;
  const float b_a = (float)i0 * (1.0f / 128.0f);
  const float b_b = (float)i1 * (1.0f / 128.0f);
  const float b_c = (float)(i1 + 1) * (1.0f / 128.0f);
  const float rb_a = spacing_inv_fn(s_near * (1.0f - b_a) + s_far * b_a);
  const float rb_b = spacing_inv_fn(s_near * (1.0f - b_b) + s_far * b_b);
  const float rb_c = spacing_inv_fn(s_near * (1.0f - b_c) + s_far * b_c);
  const float ds0 = (rb_b - rb_a) * sg.x;
  const float ds1 = (rb_c - rb_b) * sg.y;
  const float Spr = scan_incl(ds0 + ds1);
  const float E0 = Spr - (ds0 + ds1);
  const float e0 = __expf(-E0);
  const float ed0 = __expf(-ds0);
  float w00 = (1.0f - ed0) * e0;
  float w01 = (1.0f - __expf(-ds1)) * (e0 * ed0);
  if (w00 != w00) w00 = 0.0f;  // nan_to_num
  if (w01 != w01) w01 = 0.0f;

  // ---- pdf/cdf: one scan, total from lane 63 via readlane (SALU)
  const float wp0 = w00 + 0.01f, wp1 = w01 + 0.01f;
  const float S2 = scan_incl(wp0 + wp1);
  const float rt = frcp(rl63(S2));
  s_cdf[wv][i0 + 1] = fminf((S2 - wp1) * rt, 1.0f);
  s_cdf[wv][i1 + 1] = fminf(S2 * rt, 1.0f);
  if (lane == 0) s_cdf[wv][0] = 0.0f;
  s_cdf[wv][129 + lane] = 2.0f;   // sentinels 129..192 (max probe index is 191)
  wave_lds_sync();

  // ---- inverse-CDF sampling of 65 new bins (branchless 8-step search)
  auto sample_one = [&](int j) -> float {
    const float u = ((float)j + 0.5f) * (1.0f / 65.0f);
    const int c = count_le<128>(&s_cdf[wv][0], u);    // in [1,128]
    const float c0 = s_cdf[wv][c - 1], c1 = s_cdf[wv][c];
    const float b0 = (float)(c - 1) * (1.0f / 128.0f);
    float t = (u - c0) * frcp(c1 - c0);
    t = fminf(fmaxf(t, 0.0f), 1.0f);  // NaN->0, inf->1 == nan_to_num+clip
    const float bvv = b0 + t * (1.0f / 128.0f);
    s_bins1[wv][j] = bvv;
    return bvv;
  };
  const float bv = sample_one(lane);
  float bv64 = 0.0f;
  if (lane == 63) bv64 = sample_one(64);
  s_bins1[wv][65 + lane] = 2.0f;                      // sentinel pad 65..128
  float bvn = __shfl_down(bv, 1, 64);                 // bins1[lane+1]
  if (lane == 63) bvn = bv64;

  // ---- fine level: lane owns sample t=lane
  const float rbl  = spacing_inv_fn(s_near * (1.0f - bv)  + s_far * bv);
  const float rbl1 = spacing_inv_fn(s_near * (1.0f - bvn) + s_far * bvn);
  const float dsf = (rbl1 - rbl) * sgf;
  const float Sf = scan_incl(dsf);
  float w1 = (1.0f - __expf(-dsf)) * __expf(-(Sf - dsf));
  if (w1 != w1) w1 = 0.0f;
  const float tmid = 0.5f * (rbl + rbl1);

  // xyz + MERF contraction
  float px = ro[0] + rd[0] * tmid;
  float py = ro[1] + rd[1] * tmid;
  float pz = ro[2] + rd[2] * tmid;
  float cx = px, cy = py, cz = pz;
  {
    float ax = fabsf(px), ay = fabsf(py), az = fabsf(pz);
    float mag = fmaxf(ax, fmaxf(ay, az));
    if (mag >= 1.0f) {
      float inv = frcp(mag);
      float so = (2.0f - inv) * inv;
      int idx = (ax >= ay && ax >= az) ? 0 : ((ay >= az) ? 1 : 2);
      cx = px * (idx == 0 ? so : inv);
      cy = py * (idx == 1 ? so : inv);
      cz = pz * (idx == 2 ? so : inv);
    }
  }

  const float Scw = scan_incl(w1);
  const float wsum = rl63(Scw);
  const float depth_h = reduce_hi(w1 * tmid);   // totals valid lanes 48-63
  const float fx_h = reduce_hi(w1 * cx);
  const float fy_h = reduce_hi(w1 * cy);
  const float fz_h = reduce_hi(w1 * cz);
  s_cw1[wv][lane + 1] = Scw;
  if (lane == 0) s_cw1[wv][0] = 0.0f;

  // ---- distortion loss
  const float interval = bvn - bv;
  const float mid = bv + interval * 0.5f;
  const float wm = w1 * mid;
  const float Swm = scan_incl(wm);
  const float dl = (1.0f / 3.0f) * (interval * w1 * w1) +
                   2.0f * (wm * (Scw - w1) - w1 * (Swm - wm));
  const float dist_h = reduce_hi(dl);
  wave_lds_sync();  // covers s_bins1(+pad) and s_cw1 before interlevel reads

  // ---- interlevel loss: lane handles i = 2l, 2l+1 (branchless searches)
  float prop_lane = 0.0f;
  {
    const float* b1p = &s_bins1[wv][0];
    const float* cwp = &s_cw1[wv][0];
#pragma unroll
    for (int k = 0; k < 2; ++k) {
      int i = 2 * lane + k;
      float w0v = (k == 0) ? w00 : w01;
      float vlo = (float)i * (1.0f / 128.0f);
      float vhi = (float)(i + 1) * (1.0f / 128.0f);
      int ilo = max(min(count_le<64>(b1p, vlo) - 1, 63), 0);
      int ihi = min(count_le<64>(b1p + 1, vhi), 63);
      float wint = cwp[ihi + 1] - cwp[ilo];
      float diff = fmaxf(w0v - wint, 0.0f);
      prop_lane += diff * diff * frcp(w0v + 1e-8f);
    }
  }
  const float prop_h = reduce_hi(prop_lane);

  // ---- color pipeline: fuse w_view matvec BEFORE the wave reduction
  float acc0, acc1, acc2;
  {
    const float wv0 = __shfl(w1, tg, 64);
    const float wv1 = __shfl(w1, tg + 16, 64);
    const float wv2 = __shfl(w1, tg + 32, 64);
    const float wv3 = __shfl(w1, tg + 48, 64);
    const float a0 = fmaf(wv0, cva.x, fmaf(wv1, cvb.x, fmaf(wv2, cvc.x, wv3 * cvd.x)));
    const float a1 = fmaf(wv0, cva.y, fmaf(wv1, cvb.y, fmaf(wv2, cvc.y, wv3 * cvd.y)));
    const float a2 = fmaf(wv0, cva.z, fmaf(wv1, cvb.z, fmaf(wv2, cvc.z, wv3 * cvd.z)));
    const float a3 = fmaf(wv0, cva.w, fmaf(wv1, cvb.w, fmaf(wv2, cvc.w, wv3 * cvd.w)));
    const float* wvp = w_view + cg * 12;  // rows for channels 4cg..4cg+3
    acc0 = reduce_hi(fmaf(a0, wvp[0], fmaf(a1, wvp[3], fmaf(a2, wvp[6], a3 * wvp[9]))));
    acc1 = reduce_hi(fmaf(a0, wvp[1], fmaf(a1, wvp[4], fmaf(a2, wvp[7], a3 * wvp[10]))));
    acc2 = reduce_hi(fmaf(a0, wvp[2], fmaf(a1, wvp[5], fmaf(a2, wvp[8], a3 * wvp[11]))));
  }

  // ---- epilogue: totals live in lanes 48-63; spread writes over 48-52
  if (lane >= 48 && lane < 51) {
    const int j = lane - 48;
    float acc = (j == 0) ? acc0 : ((j == 1) ? acc1 : acc2);
    acc += b_view[j];
    out[IMG_OFF + ray * 3 + j] = frcp(1.0f + __expf(-acc)) + (1.0f - wsum);
    out[FXYZ_OFF + ray * 3 + j] = (j == 0) ? fx_h : ((j == 1) ? fy_h : fz_h);
  }
  if (lane == 51) out[DEPTH_OFF + ray] = depth_h;
  if (lane == 52) { s_scal[wv][0] = prop_h; s_scal[wv][1] = dist_h; }
  __syncthreads();  // only cross-wave communication in the kernel
  if (threadIdx.x == 0) {
    float P = s_scal[0][0] + s_scal[1][0] + s_scal[2][0] + s_scal[3][0];
    float D = s_scal[0][1] + s_scal[1][1] + s_scal[2][1] + s_scal[3][1];
    if (use_atomic) {
      atomicAdd(out + PROP_OFF, P * (1.0f / ((float)NRAYS * 128.0f)));
      atomicAdd(out + DIST_OFF, D * (1.0f / (float)NRAYS));
    } else {
      ws_partials[blockIdx.x] = P;
      ws_partials[NBLK + blockIdx.x] = D;
    }
  }
}

__device__ __forceinline__ float wave_sum_shfl(float x) {
#pragma unroll
  for (int off = 1; off < 64; off <<= 1) x += __shfl_xor(x, off, 64);
  return x;
}

__global__ void __launch_bounds__(256) reduce_partials(const float* __restrict__ ws,
                                                       float* __restrict__ out) {
  const float4* w4 = (const float4*)ws;
  float p = 0.0f, d = 0.0f;
  for (int i = threadIdx.x; i < NBLK / 4; i += 256) {
    float4 a = w4[i];
    p += (a.x + a.y) + (a.z + a.w);
    float4 b = w4[NBLK / 4 + i];
    d += (b.x + b.y) + (b.z + b.w);
  }
  p = wave_sum_shfl(p);
  d = wave_sum_shfl(d);
  __shared__ float sp[4], sd[4];
  const int wv = threadIdx.x >> 6, lane = threadIdx.x & 63;
  if (lane == 0) { sp[wv] = p; sd[wv] = d; }
  __syncthreads();
  if (threadIdx.x == 0) {
    float P = sp[0] + sp[1] + sp[2] + sp[3];
    float D = sd[0] + sd[1] + sd[2] + sd[3];
    out[PROP_OFF] = P * (1.0f / ((float)NRAYS * 128.0f));
    out[DIST_OFF] = D * (1.0f / (float)NRAYS);
  }
}

extern "C" void kernel_launch(void* const* d_in, const int* in_sizes, int n_in,
                              void* d_out, int out_size, void* d_ws, size_t ws_size,
                              hipStream_t stream) {
  const float* rays_o = (const float*)d_in[0];
  const float* rays_d = (const float*)d_in[1];
  const float* aabb = (const float*)d_in[2];
  const float* sig_c = (const float*)d_in[3];
  const float* sig_f = (const float*)d_in[4];
  const float* colors = (const float*)d_in[5];
  const float* w_view = (const float*)d_in[6];
  const float* b_view = (const float*)d_in[7];
  float* out = (float*)d_out;
  float* wsf = (float*)d_ws;

  const bool use_ws = (ws_size >= (size_t)(2 * NBLK) * sizeof(float)) && (wsf != nullptr);
  if (!use_ws) {
    hipMemsetAsync(out + PROP_OFF, 0, 2 * sizeof(float), stream);
  }
  nerf_main<<<NBLK, 256, 0, stream>>>(rays_o, rays_d, aabb, sig_c, sig_f, colors,
                                      w_view, b_view, out, wsf, use_ws ? 0 : 1);
  if (use_ws) reduce_partials<<<1, 256, 0, stream>>>(wsf, out);
}